// Round 2
// baseline (14486.868 us; speedup 1.0000x reference)
//
#include <hip/hip_runtime.h>
#include <cstdio>

#define B_   256
#define H_   512
#define G4_  2048
#define T_   326
#define OUT_ 9

typedef __attribute__((ext_vector_type(8))) short s16x8;
typedef __attribute__((ext_vector_type(4))) float f32x4;

__device__ inline unsigned short to_bf16(float f) {
    unsigned int u = __builtin_bit_cast(unsigned int, f);
    unsigned int r = (u + 0x7fffu + ((u >> 16) & 1u)) >> 16;  // RNE
    return (unsigned short)r;
}

__device__ inline float sigmoidf_(float x) { return 1.0f / (1.0f + __expf(-x)); }

__device__ inline float fast_tanh(float x) {
    x = fminf(fmaxf(x, -15.f), 15.f);
    float e = __expf(2.f * x);
    return (e - 1.f) / (e + 1.f);
}

// ---------------- prep kernels ----------------

__global__ void prep_weights(const float* __restrict__ Wih, const float* __restrict__ Whh,
                             const float* __restrict__ bih, const float* __restrict__ bhh,
                             unsigned short* __restrict__ Wc, unsigned short* __restrict__ Wcat,
                             float* __restrict__ bc) {
    int idx = blockIdx.x * 256 + threadIdx.x;      // < 2048*512
    int n = idx >> 9, k = idx & 511;
    float wi = Wih[idx], wh = Whh[idx];
    Wc[idx] = to_bf16(wi + wh);
    Wcat[(n << 10) + k]       = to_bf16(wi);
    Wcat[(n << 10) + 512 + k] = to_bf16(wh);
    if (k == 0) bc[n] = bih[n] + bhh[n];
}

__global__ void prep_w1(const float* __restrict__ W1, unsigned short* __restrict__ W1b) {
    int idx = blockIdx.x * 256 + threadIdx.x;      // < 512*512
    W1b[idx] = to_bf16(W1[idx]);
}

__global__ void prep_w2(const float* __restrict__ W2, unsigned short* __restrict__ W2b) {
    int idx = blockIdx.x * 256 + threadIdx.x;      // < 16*512
    int o = idx >> 9, k = idx & 511;
    W2b[idx] = (o < OUT_) ? to_bf16(W2[o * H_ + k]) : (unsigned short)0;
}

__global__ void prep_x(const float* __restrict__ x, const float* __restrict__ hx0,
                       unsigned short* __restrict__ xcat) {
    int idx = blockIdx.x * 256 + threadIdx.x;      // < 256*512
    int b = idx >> 9, k = idx & 511;
    xcat[(b << 10) + k]       = to_bf16(x[idx]);
    xcat[(b << 10) + 512 + k] = to_bf16(hx0[idx]);
}

// ---------------- step 0 (K=1024, [x|hx0] @ [Wih|Whh]) ----------------
template <int KLEN>
__global__ __launch_bounds__(256) void lstm_step(
    const unsigned short* __restrict__ A,
    const unsigned short* __restrict__ W,
    const float* __restrict__ bc,
    const float* __restrict__ c_in,
    float* __restrict__ c_out,
    unsigned short* __restrict__ h_out) {
    const int lane = threadIdx.x & 63;
    const int wave = threadIdx.x >> 6;
    const int mn = lane & 15, q = lane >> 4;
    const int rt = blockIdx.x & 15;
    const int hb = (blockIdx.x >> 4) * 64 + wave * 16;

    const unsigned short* ap  = A + (size_t)(rt * 16 + mn) * KLEN + q * 8;
    const unsigned short* wp0 = W + (size_t)(0 * H_ + hb + mn) * KLEN + q * 8;
    const unsigned short* wp1 = W + (size_t)(1 * H_ + hb + mn) * KLEN + q * 8;
    const unsigned short* wp2 = W + (size_t)(2 * H_ + hb + mn) * KLEN + q * 8;
    const unsigned short* wp3 = W + (size_t)(3 * H_ + hb + mn) * KLEN + q * 8;

    f32x4 acc0 = {0.f,0.f,0.f,0.f}, acc1 = {0.f,0.f,0.f,0.f};
    f32x4 acc2 = {0.f,0.f,0.f,0.f}, acc3 = {0.f,0.f,0.f,0.f};
#pragma unroll 4
    for (int k0 = 0; k0 < KLEN; k0 += 32) {
        s16x8 a  = *reinterpret_cast<const s16x8*>(ap + k0);
        s16x8 w0 = *reinterpret_cast<const s16x8*>(wp0 + k0);
        s16x8 w1 = *reinterpret_cast<const s16x8*>(wp1 + k0);
        s16x8 w2 = *reinterpret_cast<const s16x8*>(wp2 + k0);
        s16x8 w3 = *reinterpret_cast<const s16x8*>(wp3 + k0);
        acc0 = __builtin_amdgcn_mfma_f32_16x16x32_bf16(a, w0, acc0, 0, 0, 0);
        acc1 = __builtin_amdgcn_mfma_f32_16x16x32_bf16(a, w1, acc1, 0, 0, 0);
        acc2 = __builtin_amdgcn_mfma_f32_16x16x32_bf16(a, w2, acc2, 0, 0, 0);
        acc3 = __builtin_amdgcn_mfma_f32_16x16x32_bf16(a, w3, acc3, 0, 0, 0);
    }

    const int j = hb + mn;
    const float bi = bc[j], bfv = bc[H_ + j], bg = bc[2 * H_ + j], bo = bc[3 * H_ + j];
#pragma unroll
    for (int r = 0; r < 4; ++r) {
        const int row = rt * 16 + q * 4 + r;
        const float iv = sigmoidf_(acc0[r] + bi);
        const float fv = sigmoidf_(acc1[r] + bfv);
        const float gv = fast_tanh(acc2[r] + bg);
        const float ov = sigmoidf_(acc3[r] + bo);
        const float co = c_in[row * H_ + j];
        const float cn = fv * co + iv * gv;
        c_out[row * H_ + j] = cn;
        h_out[row * H_ + j] = to_bf16(ov * fast_tanh(cn));
    }
}

// ---------------- persistent LSTM (steps 1..325) ----------------
// 256 WGs x 256 thr (cooperative). WG = (mt: 8 x 32 rows) x (16 hidden cols).
// wave = gate index (0=i,1=f,2=g,3=o); its 16x512 weight slice lives in 64
// VGPRs for the whole kernel. c: 2 fp32 regs/thread for all steps.
// Per step: stage 32x512 h-slice -> LDS (stride 520: conflict-free b128),
// 32 MFMAs/wave, activations -> gate LDS, c/h update, device-scope barrier.
__global__ __launch_bounds__(256) void lstm_persist(
    const unsigned short* __restrict__ Wc,   // [2048][512] bf16
    const float* __restrict__ bc,            // [2048]
    const float* __restrict__ c0,            // [256][512] f32 (from step 0)
    unsigned short* __restrict__ h_hist,     // [326][256][512] bf16
    unsigned int* __restrict__ ctr) {
    constexpr int AS = 520;                      // ushort stride (pad 8)
    __shared__ unsigned short A_lds[32 * AS];    // 33280 B
    __shared__ float gate_lds[4 * 32 * 17];      // 8704 B
    const int tid = threadIdx.x;
    const int lane = tid & 63, wave = tid >> 6;
    const int mn = lane & 15, q = lane >> 4;
    const int mt = blockIdx.x >> 5;
    const int jb = (blockIdx.x & 31) * 16;

    // weights -> registers (B-fragment layout: n=mn, k=kk*32+q*8)
    s16x8 breg[16];
    {
        const unsigned short* wp = Wc + (size_t)(wave * H_ + jb + mn) * H_ + q * 8;
#pragma unroll
        for (int kk = 0; kk < 16; ++kk) breg[kk] = *reinterpret_cast<const s16x8*>(wp + kk * 32);
    }
    const float bcv = bc[wave * H_ + jb + mn];

    const int crow = tid >> 4, cj = tid & 15;    // owned c/h elements
    float c_a = c0[(size_t)(mt * 32 + crow) * H_ + jb + cj];
    float c_b = c0[(size_t)(mt * 32 + crow + 16) * H_ + jb + cj];

    for (int t = 1; t < T_; ++t) {
        // ---- stage A = h_{t-1} rows [mt*32, mt*32+32) ----
        const unsigned short* hsrc = h_hist + (size_t)(t - 1) * (B_ * H_) + (size_t)mt * 32 * H_;
#pragma unroll
        for (int pass = 0; pass < 8; ++pass) {
            int off = pass * 2048 + tid * 8;
            s16x8 v = *reinterpret_cast<const s16x8*>(hsrc + off);
            int row = off >> 9, col = off & 511;
            *reinterpret_cast<s16x8*>(&A_lds[row * AS + col]) = v;
        }
        __syncthreads();

        // ---- gates via MFMA (M=32 as 2 subtiles, N=16, K=512) ----
        f32x4 acc0 = {0.f,0.f,0.f,0.f}, acc1 = {0.f,0.f,0.f,0.f};
#pragma unroll
        for (int kk = 0; kk < 16; ++kk) {
            s16x8 a0 = *reinterpret_cast<const s16x8*>(&A_lds[mn * AS + kk * 32 + q * 8]);
            s16x8 a1 = *reinterpret_cast<const s16x8*>(&A_lds[(16 + mn) * AS + kk * 32 + q * 8]);
            acc0 = __builtin_amdgcn_mfma_f32_16x16x32_bf16(a0, breg[kk], acc0, 0, 0, 0);
            acc1 = __builtin_amdgcn_mfma_f32_16x16x32_bf16(a1, breg[kk], acc1, 0, 0, 0);
        }

        // ---- activations -> gate LDS (C-layout: col=mn, row=q*4+r) ----
#pragma unroll
        for (int r = 0; r < 4; ++r) {
            float v0 = acc0[r] + bcv, v1 = acc1[r] + bcv;
            if (wave == 2) { v0 = fast_tanh(v0); v1 = fast_tanh(v1); }
            else           { v0 = sigmoidf_(v0); v1 = sigmoidf_(v1); }
            gate_lds[(wave * 32 + (q * 4 + r)) * 17 + mn]      = v0;
            gate_lds[(wave * 32 + (16 + q * 4 + r)) * 17 + mn] = v1;
        }
        __syncthreads();

        // ---- c/h update (2 elements per thread) ----
        unsigned short* hdst = h_hist + (size_t)t * (B_ * H_) + (size_t)mt * 32 * H_;
        {
            float iv = gate_lds[(0 * 32 + crow) * 17 + cj];
            float fv = gate_lds[(1 * 32 + crow) * 17 + cj];
            float gv = gate_lds[(2 * 32 + crow) * 17 + cj];
            float ov = gate_lds[(3 * 32 + crow) * 17 + cj];
            c_a = fv * c_a + iv * gv;
            hdst[crow * H_ + jb + cj] = to_bf16(ov * fast_tanh(c_a));

            iv = gate_lds[(0 * 32 + crow + 16) * 17 + cj];
            fv = gate_lds[(1 * 32 + crow + 16) * 17 + cj];
            gv = gate_lds[(2 * 32 + crow + 16) * 17 + cj];
            ov = gate_lds[(3 * 32 + crow + 16) * 17 + cj];
            c_b = fv * c_b + iv * gv;
            hdst[(crow + 16) * H_ + jb + cj] = to_bf16(ov * fast_tanh(c_b));
        }

        // ---- device-scope grid barrier ----
        if (t < T_ - 1) {
            __threadfence();            // release: h stores -> device scope
            __syncthreads();            // all threads' fences done before arrive
            if (tid == 0) {
                __hip_atomic_fetch_add(ctr, 1u, __ATOMIC_RELEASE, __HIP_MEMORY_SCOPE_AGENT);
                const unsigned int target = 256u * (unsigned int)t;
                while (__hip_atomic_load(ctr, __ATOMIC_RELAXED, __HIP_MEMORY_SCOPE_AGENT) < target) {
                    __builtin_amdgcn_s_sleep(1);
                }
            }
            __syncthreads();
            __threadfence();            // acquire: see other WGs' h stores
        }
    }
}

// ---------------- deferred MLP head ----------------
__global__ __launch_bounds__(256) void mlp_kernel(
    const unsigned short* __restrict__ h_hist,
    const unsigned short* __restrict__ W1b,
    const float* __restrict__ b1,
    const unsigned short* __restrict__ W2b,
    const float* __restrict__ b2,
    float* __restrict__ out) {
    constexpr int ZS = 520;
    __shared__ unsigned short z_lds[32 * ZS];

    const int lane = threadIdx.x & 63;
    const int wave = threadIdx.x >> 6;
    const int mn = lane & 15, q = lane >> 4;
    const int t = blockIdx.x >> 2, mt = blockIdx.x & 3;

    const unsigned short* Abase = h_hist + ((size_t)t * B_ + mt * 64) * H_;
    const int nb = wave * 128;

    f32x4 zero4 = {0.f,0.f,0.f,0.f};
    f32x4 acc[4][8];
#pragma unroll
    for (int m4 = 0; m4 < 4; ++m4)
#pragma unroll
        for (int nt = 0; nt < 8; ++nt) acc[m4][nt] = zero4;

    for (int k0 = 0; k0 < 512; k0 += 32) {
        s16x8 a[4];
#pragma unroll
        for (int m4 = 0; m4 < 4; ++m4)
            a[m4] = *reinterpret_cast<const s16x8*>(Abase + (size_t)(m4 * 16 + mn) * H_ + k0 + q * 8);
#pragma unroll
        for (int nt = 0; nt < 8; ++nt) {
            s16x8 b = *reinterpret_cast<const s16x8*>(W1b + (size_t)(nb + nt * 16 + mn) * H_ + k0 + q * 8);
#pragma unroll
            for (int m4 = 0; m4 < 4; ++m4)
                acc[m4][nt] = __builtin_amdgcn_mfma_f32_16x16x32_bf16(a[m4], b, acc[m4][nt], 0, 0, 0);
        }
    }

    float b1v[8];
#pragma unroll
    for (int nt = 0; nt < 8; ++nt) b1v[nt] = b1[nb + nt * 16 + mn];

    for (int pass = 0; pass < 2; ++pass) {
        __syncthreads();
#pragma unroll
        for (int m4i = 0; m4i < 2; ++m4i) {
            const int m4 = 2 * pass + m4i;
            const int rl = m4i * 16 + q * 4;
#pragma unroll
            for (int nt = 0; nt < 8; ++nt) {
                const int col = nb + nt * 16 + mn;
#pragma unroll
                for (int r = 0; r < 4; ++r) {
                    float v = acc[m4][nt][r] + b1v[nt];
                    v = v > 0.f ? v : 0.f;
                    z_lds[(rl + r) * ZS + col] = to_bf16(v);
                }
            }
        }
        __syncthreads();
        if (wave < 2) {
            f32x4 yacc = {0.f,0.f,0.f,0.f};
#pragma unroll 4
            for (int k0 = 0; k0 < 512; k0 += 32) {
                s16x8 az = *reinterpret_cast<const s16x8*>(&z_lds[(wave * 16 + mn) * ZS + k0 + q * 8]);
                s16x8 bw = *reinterpret_cast<const s16x8*>(W2b + (size_t)mn * H_ + k0 + q * 8);
                yacc = __builtin_amdgcn_mfma_f32_16x16x32_bf16(az, bw, yacc, 0, 0, 0);
            }
            if (mn < OUT_) {
                const float bias = b2[mn];
#pragma unroll
                for (int r = 0; r < 4; ++r) {
                    const int row_local = pass * 32 + wave * 16 + q * 4 + r;
                    const int b = mt * 64 + row_local;
                    out[(size_t)b * (T_ * OUT_) + t * OUT_ + mn] = yacc[r] + bias;
                }
            }
        }
    }
}

// ---------------- host launch ----------------
extern "C" void kernel_launch(void* const* d_in, const int* in_sizes, int n_in,
                              void* d_out, int out_size, void* d_ws, size_t ws_size,
                              hipStream_t stream) {
    (void)in_sizes; (void)n_in; (void)out_size;
    const float* x   = (const float*)d_in[0];
    const float* hx0 = (const float*)d_in[1];
    const float* cx0 = (const float*)d_in[2];
    const float* Wih = (const float*)d_in[3];
    const float* Whh = (const float*)d_in[4];
    const float* bih = (const float*)d_in[5];
    const float* bhh = (const float*)d_in[6];
    const float* W1  = (const float*)d_in[7];
    const float* b1  = (const float*)d_in[8];
    const float* W2  = (const float*)d_in[9];
    const float* b2  = (const float*)d_in[10];
    float* out = (float*)d_out;

    char* p = (char*)d_ws;
    size_t off = 0;
    auto alloc = [&](size_t bytes) {
        void* r = p + off;
        off = (off + bytes + 255) & ~(size_t)255;
        return r;
    };
    unsigned short* Wc     = (unsigned short*)alloc((size_t)G4_ * H_ * 2);
    unsigned short* Wcat   = (unsigned short*)alloc((size_t)G4_ * 1024 * 2);
    unsigned short* W1b    = (unsigned short*)alloc((size_t)H_ * H_ * 2);
    unsigned short* W2b    = (unsigned short*)alloc((size_t)16 * H_ * 2);
    float*          bc     = (float*)alloc((size_t)G4_ * 4);
    unsigned short* xcat   = (unsigned short*)alloc((size_t)B_ * 1024 * 2);
    float*          cbuf   = (float*)alloc((size_t)B_ * H_ * 4);
    unsigned short* h_hist = (unsigned short*)alloc((size_t)T_ * B_ * H_ * 2);
    if (off > ws_size) {
        fprintf(stderr, "kernel_launch: ws too small: need %zu have %zu\n", off, ws_size);
        return;
    }
    // barrier counter: reuse xcat space (xcat dead after step-0 kernel)
    unsigned int* ctr = (unsigned int*)xcat;

    prep_weights<<<G4_ * H_ / 256, 256, 0, stream>>>(Wih, Whh, bih, bhh, Wc, Wcat, bc);
    prep_w1<<<H_ * H_ / 256, 256, 0, stream>>>(W1, W1b);
    prep_w2<<<16 * H_ / 256, 256, 0, stream>>>(W2, W2b);
    prep_x<<<B_ * H_ / 256, 256, 0, stream>>>(x, hx0, xcat);

    // step 0: K=1024
    lstm_step<1024><<<128, 256, 0, stream>>>(xcat, Wcat, bc, cx0, cbuf, h_hist);

    // zero the barrier counter (xcat is dead now), then persistent steps 1..325
    hipMemsetAsync(ctr, 0, 64, stream);
    {
        const unsigned short* Wc_l = Wc;
        const float* bc_l = bc;
        const float* c0_l = cbuf;
        unsigned short* hh_l = h_hist;
        unsigned int* ctr_l = ctr;
        void* args[5] = {(void*)&Wc_l, (void*)&bc_l, (void*)&c0_l, (void*)&hh_l, (void*)&ctr_l};
        hipLaunchCooperativeKernel((const void*)lstm_persist, dim3(256), dim3(256), args, 0, stream);
    }

    mlp_kernel<<<T_ * 4, 256, 0, stream>>>(h_hist, W1b, b1, W2b, b2, out);
}

// Round 3
// 1208.971 us; speedup vs baseline: 11.9828x; 11.9828x over previous
//
#include <hip/hip_runtime.h>
#include <cstdio>

#define B_   256
#define H_   512
#define G4_  2048
#define T_   326
#define OUT_ 9

typedef __attribute__((ext_vector_type(8))) short s16x8;
typedef __attribute__((ext_vector_type(4))) float f32x4;

__device__ inline unsigned short to_bf16(float f) {
    unsigned int u = __builtin_bit_cast(unsigned int, f);
    unsigned int r = (u + 0x7fffu + ((u >> 16) & 1u)) >> 16;  // RNE
    return (unsigned short)r;
}

__device__ inline float sigmoidf_(float x) { return 1.0f / (1.0f + __expf(-x)); }

__device__ inline float fast_tanh(float x) {
    x = fminf(fmaxf(x, -15.f), 15.f);
    float e = __expf(2.f * x);
    return (e - 1.f) / (e + 1.f);
}

// ---------------- prep kernels ----------------

__global__ void prep_weights(const float* __restrict__ Wih, const float* __restrict__ Whh,
                             const float* __restrict__ bih, const float* __restrict__ bhh,
                             unsigned short* __restrict__ Wc, unsigned short* __restrict__ Wcat,
                             float* __restrict__ bc) {
    int idx = blockIdx.x * 256 + threadIdx.x;      // < 2048*512
    int n = idx >> 9, k = idx & 511;
    float wi = Wih[idx], wh = Whh[idx];
    Wc[idx] = to_bf16(wi + wh);
    Wcat[(n << 10) + k]       = to_bf16(wi);
    Wcat[(n << 10) + 512 + k] = to_bf16(wh);
    if (k == 0) bc[n] = bih[n] + bhh[n];
}

__global__ void prep_w1(const float* __restrict__ W1, unsigned short* __restrict__ W1b) {
    int idx = blockIdx.x * 256 + threadIdx.x;      // < 512*512
    W1b[idx] = to_bf16(W1[idx]);
}

__global__ void prep_w2(const float* __restrict__ W2, unsigned short* __restrict__ W2b) {
    int idx = blockIdx.x * 256 + threadIdx.x;      // < 16*512
    int o = idx >> 9, k = idx & 511;
    W2b[idx] = (o < OUT_) ? to_bf16(W2[o * H_ + k]) : (unsigned short)0;
}

__global__ void prep_x(const float* __restrict__ x, const float* __restrict__ hx0,
                       unsigned short* __restrict__ xcat) {
    int idx = blockIdx.x * 256 + threadIdx.x;      // < 256*512
    int b = idx >> 9, k = idx & 511;
    xcat[(b << 10) + k]       = to_bf16(x[idx]);
    xcat[(b << 10) + 512 + k] = to_bf16(hx0[idx]);
}

// ---------------- step 0 (K=1024, [x|hx0] @ [Wih|Whh]) ----------------
template <int KLEN>
__global__ __launch_bounds__(256) void lstm_step(
    const unsigned short* __restrict__ A,
    const unsigned short* __restrict__ W,
    const float* __restrict__ bc,
    const float* __restrict__ c_in,
    float* __restrict__ c_out,
    unsigned short* __restrict__ h_out) {
    const int lane = threadIdx.x & 63;
    const int wave = threadIdx.x >> 6;
    const int mn = lane & 15, q = lane >> 4;
    const int rt = blockIdx.x & 15;
    const int hb = (blockIdx.x >> 4) * 64 + wave * 16;

    const unsigned short* ap  = A + (size_t)(rt * 16 + mn) * KLEN + q * 8;
    const unsigned short* wp0 = W + (size_t)(0 * H_ + hb + mn) * KLEN + q * 8;
    const unsigned short* wp1 = W + (size_t)(1 * H_ + hb + mn) * KLEN + q * 8;
    const unsigned short* wp2 = W + (size_t)(2 * H_ + hb + mn) * KLEN + q * 8;
    const unsigned short* wp3 = W + (size_t)(3 * H_ + hb + mn) * KLEN + q * 8;

    f32x4 acc0 = {0.f,0.f,0.f,0.f}, acc1 = {0.f,0.f,0.f,0.f};
    f32x4 acc2 = {0.f,0.f,0.f,0.f}, acc3 = {0.f,0.f,0.f,0.f};
#pragma unroll 4
    for (int k0 = 0; k0 < KLEN; k0 += 32) {
        s16x8 a  = *reinterpret_cast<const s16x8*>(ap + k0);
        s16x8 w0 = *reinterpret_cast<const s16x8*>(wp0 + k0);
        s16x8 w1 = *reinterpret_cast<const s16x8*>(wp1 + k0);
        s16x8 w2 = *reinterpret_cast<const s16x8*>(wp2 + k0);
        s16x8 w3 = *reinterpret_cast<const s16x8*>(wp3 + k0);
        acc0 = __builtin_amdgcn_mfma_f32_16x16x32_bf16(a, w0, acc0, 0, 0, 0);
        acc1 = __builtin_amdgcn_mfma_f32_16x16x32_bf16(a, w1, acc1, 0, 0, 0);
        acc2 = __builtin_amdgcn_mfma_f32_16x16x32_bf16(a, w2, acc2, 0, 0, 0);
        acc3 = __builtin_amdgcn_mfma_f32_16x16x32_bf16(a, w3, acc3, 0, 0, 0);
    }

    const int j = hb + mn;
    const float bi = bc[j], bfv = bc[H_ + j], bg = bc[2 * H_ + j], bo = bc[3 * H_ + j];
#pragma unroll
    for (int r = 0; r < 4; ++r) {
        const int row = rt * 16 + q * 4 + r;
        const float iv = sigmoidf_(acc0[r] + bi);
        const float fv = sigmoidf_(acc1[r] + bfv);
        const float gv = fast_tanh(acc2[r] + bg);
        const float ov = sigmoidf_(acc3[r] + bo);
        const float co = c_in[row * H_ + j];
        const float cn = fv * co + iv * gv;
        c_out[row * H_ + j] = cn;
        h_out[row * H_ + j] = to_bf16(ov * fast_tanh(cn));
    }
}

// ---------------- persistent LSTM (steps 1..325) ----------------
// 256 WGs x 256 thr (cooperative). 8 INDEPENDENT groups: mt = blockIdx&7 owns
// rows [mt*32, mt*32+32); jb = (blockIdx>>3)*16 hidden cols. Rows evolve
// independently -> only the 32 WGs sharing mt must sync, on their own counter.
// NO __threadfence / release atomics (those emit buffer_wbl2/inv sc1 = full-L2
// walks, the R2 disaster). All cross-WG data ops are sc1 (relaxed AGENT
// atomics); completion via the vmcnt(0) drain inside __syncthreads().
__global__ __launch_bounds__(256) void lstm_persist(
    const unsigned short* __restrict__ Wc,   // [2048][512] bf16
    const float* __restrict__ bc,            // [2048]
    const float* __restrict__ c0,            // [256][512] f32 (from step 0)
    unsigned short* __restrict__ h_hist,     // [326][256][512] bf16
    unsigned int* __restrict__ ctr) {        // 8 counters, 128B apart
    constexpr int AS = 520;                      // ushort stride (pad 8)
    __shared__ unsigned short A_lds[32 * AS];    // 33280 B
    __shared__ float gate_lds[4 * 32 * 17];      // 8704 B
    const int tid = threadIdx.x;
    const int lane = tid & 63, wave = tid >> 6;
    const int mn = lane & 15, q = lane >> 4;
    const int mt = blockIdx.x & 7;               // group = likely same XCD
    const int jb = (blockIdx.x >> 3) * 16;
    unsigned int* ctr_g = ctr + mt * 32;         // own cacheline per group

    // weights -> registers (B-fragment layout: n=mn, k=kk*32+q*8)
    s16x8 breg[16];
    {
        const unsigned short* wp = Wc + (size_t)(wave * H_ + jb + mn) * H_ + q * 8;
#pragma unroll
        for (int kk = 0; kk < 16; ++kk) breg[kk] = *reinterpret_cast<const s16x8*>(wp + kk * 32);
    }
    const float bcv = bc[wave * H_ + jb + mn];

    // owned c/h elements: row = tid>>3 (0..31), cols c0..c0+1 (c0 = 2*(tid&7))
    const int crow = tid >> 3, cc0 = (tid & 7) * 2;
    float c_x = c0[(size_t)(mt * 32 + crow) * H_ + jb + cc0];
    float c_y = c0[(size_t)(mt * 32 + crow) * H_ + jb + cc0 + 1];

    for (int t = 1; t < T_; ++t) {
        // ---- stage A = h_{t-1} rows [mt*32, mt*32+32) via sc1 8B loads ----
        const unsigned long long* hsrc64 = reinterpret_cast<const unsigned long long*>(
            h_hist + (size_t)(t - 1) * (B_ * H_) + (size_t)mt * 32 * H_);
        unsigned long long vv[16];
#pragma unroll
        for (int p = 0; p < 16; ++p)
            vv[p] = __hip_atomic_load(hsrc64 + p * 256 + tid, __ATOMIC_RELAXED,
                                      __HIP_MEMORY_SCOPE_AGENT);
#pragma unroll
        for (int p = 0; p < 16; ++p) {
            int qi = p * 256 + tid;
            int row = qi >> 7;                 // 128 qwords per 512-col row
            int col = (qi & 127) << 2;
            *reinterpret_cast<unsigned long long*>(&A_lds[row * AS + col]) = vv[p];
        }
        __syncthreads();

        // ---- gates via MFMA (M=32 as 2 subtiles, N=16, K=512) ----
        f32x4 acc0 = {0.f,0.f,0.f,0.f}, acc1 = {0.f,0.f,0.f,0.f};
#pragma unroll
        for (int kk = 0; kk < 16; ++kk) {
            s16x8 a0 = *reinterpret_cast<const s16x8*>(&A_lds[mn * AS + kk * 32 + q * 8]);
            s16x8 a1 = *reinterpret_cast<const s16x8*>(&A_lds[(16 + mn) * AS + kk * 32 + q * 8]);
            acc0 = __builtin_amdgcn_mfma_f32_16x16x32_bf16(a0, breg[kk], acc0, 0, 0, 0);
            acc1 = __builtin_amdgcn_mfma_f32_16x16x32_bf16(a1, breg[kk], acc1, 0, 0, 0);
        }

        // ---- activations -> gate LDS (C-layout: col=mn, row=q*4+r) ----
#pragma unroll
        for (int r = 0; r < 4; ++r) {
            float v0 = acc0[r] + bcv, v1 = acc1[r] + bcv;
            if (wave == 2) { v0 = fast_tanh(v0); v1 = fast_tanh(v1); }
            else           { v0 = sigmoidf_(v0); v1 = sigmoidf_(v1); }
            gate_lds[(wave * 32 + (q * 4 + r)) * 17 + mn]      = v0;
            gate_lds[(wave * 32 + (16 + q * 4 + r)) * 17 + mn] = v1;
        }
        __syncthreads();

        // ---- c/h update (2 adjacent cols of one row per thread) ----
        {
            float iv0 = gate_lds[(0 * 32 + crow) * 17 + cc0], iv1 = gate_lds[(0 * 32 + crow) * 17 + cc0 + 1];
            float fv0 = gate_lds[(1 * 32 + crow) * 17 + cc0], fv1 = gate_lds[(1 * 32 + crow) * 17 + cc0 + 1];
            float gv0 = gate_lds[(2 * 32 + crow) * 17 + cc0], gv1 = gate_lds[(2 * 32 + crow) * 17 + cc0 + 1];
            float ov0 = gate_lds[(3 * 32 + crow) * 17 + cc0], ov1 = gate_lds[(3 * 32 + crow) * 17 + cc0 + 1];
            c_x = fv0 * c_x + iv0 * gv0;
            c_y = fv1 * c_y + iv1 * gv1;
            unsigned int h0 = to_bf16(ov0 * fast_tanh(c_x));
            unsigned int h1 = to_bf16(ov1 * fast_tanh(c_y));
            unsigned int packed = h0 | (h1 << 16);
            unsigned int* hdst = reinterpret_cast<unsigned int*>(
                h_hist + (size_t)t * (B_ * H_) + (size_t)(mt * 32 + crow) * H_ + jb + cc0);
            __hip_atomic_store(hdst, packed, __ATOMIC_RELAXED, __HIP_MEMORY_SCOPE_AGENT);
        }

        // ---- per-group barrier (32 WGs), no cache-maintenance ops ----
        if (t < T_ - 1) {
            __syncthreads();  // emits s_waitcnt vmcnt(0): sc1 h-stores complete
            asm volatile("" ::: "memory");
            if (tid == 0) {
                __hip_atomic_fetch_add(ctr_g, 1u, __ATOMIC_RELAXED, __HIP_MEMORY_SCOPE_AGENT);
                const unsigned int target = 32u * (unsigned int)t;
                while (__hip_atomic_load(ctr_g, __ATOMIC_RELAXED, __HIP_MEMORY_SCOPE_AGENT) < target) {
                }
            }
            asm volatile("" ::: "memory");
            __syncthreads();
        }
    }
}

// ---------------- deferred MLP head ----------------
__global__ __launch_bounds__(256) void mlp_kernel(
    const unsigned short* __restrict__ h_hist,
    const unsigned short* __restrict__ W1b,
    const float* __restrict__ b1,
    const unsigned short* __restrict__ W2b,
    const float* __restrict__ b2,
    float* __restrict__ out) {
    constexpr int ZS = 520;
    __shared__ unsigned short z_lds[32 * ZS];

    const int lane = threadIdx.x & 63;
    const int wave = threadIdx.x >> 6;
    const int mn = lane & 15, q = lane >> 4;
    const int t = blockIdx.x >> 2, mt = blockIdx.x & 3;

    const unsigned short* Abase = h_hist + ((size_t)t * B_ + mt * 64) * H_;
    const int nb = wave * 128;

    f32x4 zero4 = {0.f,0.f,0.f,0.f};
    f32x4 acc[4][8];
#pragma unroll
    for (int m4 = 0; m4 < 4; ++m4)
#pragma unroll
        for (int nt = 0; nt < 8; ++nt) acc[m4][nt] = zero4;

    for (int k0 = 0; k0 < 512; k0 += 32) {
        s16x8 a[4];
#pragma unroll
        for (int m4 = 0; m4 < 4; ++m4)
            a[m4] = *reinterpret_cast<const s16x8*>(Abase + (size_t)(m4 * 16 + mn) * H_ + k0 + q * 8);
#pragma unroll
        for (int nt = 0; nt < 8; ++nt) {
            s16x8 b = *reinterpret_cast<const s16x8*>(W1b + (size_t)(nb + nt * 16 + mn) * H_ + k0 + q * 8);
#pragma unroll
            for (int m4 = 0; m4 < 4; ++m4)
                acc[m4][nt] = __builtin_amdgcn_mfma_f32_16x16x32_bf16(a[m4], b, acc[m4][nt], 0, 0, 0);
        }
    }

    float b1v[8];
#pragma unroll
    for (int nt = 0; nt < 8; ++nt) b1v[nt] = b1[nb + nt * 16 + mn];

    for (int pass = 0; pass < 2; ++pass) {
        __syncthreads();
#pragma unroll
        for (int m4i = 0; m4i < 2; ++m4i) {
            const int m4 = 2 * pass + m4i;
            const int rl = m4i * 16 + q * 4;
#pragma unroll
            for (int nt = 0; nt < 8; ++nt) {
                const int col = nb + nt * 16 + mn;
#pragma unroll
                for (int r = 0; r < 4; ++r) {
                    float v = acc[m4][nt][r] + b1v[nt];
                    v = v > 0.f ? v : 0.f;
                    z_lds[(rl + r) * ZS + col] = to_bf16(v);
                }
            }
        }
        __syncthreads();
        if (wave < 2) {
            f32x4 yacc = {0.f,0.f,0.f,0.f};
#pragma unroll 4
            for (int k0 = 0; k0 < 512; k0 += 32) {
                s16x8 az = *reinterpret_cast<const s16x8*>(&z_lds[(wave * 16 + mn) * ZS + k0 + q * 8]);
                s16x8 bw = *reinterpret_cast<const s16x8*>(W2b + (size_t)mn * H_ + k0 + q * 8);
                yacc = __builtin_amdgcn_mfma_f32_16x16x32_bf16(az, bw, yacc, 0, 0, 0);
            }
            if (mn < OUT_) {
                const float bias = b2[mn];
#pragma unroll
                for (int r = 0; r < 4; ++r) {
                    const int row_local = pass * 32 + wave * 16 + q * 4 + r;
                    const int b = mt * 64 + row_local;
                    out[(size_t)b * (T_ * OUT_) + t * OUT_ + mn] = yacc[r] + bias;
                }
            }
        }
    }
}

// ---------------- host launch ----------------
extern "C" void kernel_launch(void* const* d_in, const int* in_sizes, int n_in,
                              void* d_out, int out_size, void* d_ws, size_t ws_size,
                              hipStream_t stream) {
    (void)in_sizes; (void)n_in; (void)out_size;
    const float* x   = (const float*)d_in[0];
    const float* hx0 = (const float*)d_in[1];
    const float* cx0 = (const float*)d_in[2];
    const float* Wih = (const float*)d_in[3];
    const float* Whh = (const float*)d_in[4];
    const float* bih = (const float*)d_in[5];
    const float* bhh = (const float*)d_in[6];
    const float* W1  = (const float*)d_in[7];
    const float* b1  = (const float*)d_in[8];
    const float* W2  = (const float*)d_in[9];
    const float* b2  = (const float*)d_in[10];
    float* out = (float*)d_out;

    char* p = (char*)d_ws;
    size_t off = 0;
    auto alloc = [&](size_t bytes) {
        void* r = p + off;
        off = (off + bytes + 255) & ~(size_t)255;
        return r;
    };
    unsigned short* Wc     = (unsigned short*)alloc((size_t)G4_ * H_ * 2);
    unsigned short* Wcat   = (unsigned short*)alloc((size_t)G4_ * 1024 * 2);
    unsigned short* W1b    = (unsigned short*)alloc((size_t)H_ * H_ * 2);
    unsigned short* W2b    = (unsigned short*)alloc((size_t)16 * H_ * 2);
    float*          bc     = (float*)alloc((size_t)G4_ * 4);
    unsigned short* xcat   = (unsigned short*)alloc((size_t)B_ * 1024 * 2);
    float*          cbuf   = (float*)alloc((size_t)B_ * H_ * 4);
    unsigned int*   ctr    = (unsigned int*)alloc(4096);
    unsigned short* h_hist = (unsigned short*)alloc((size_t)T_ * B_ * H_ * 2);
    if (off > ws_size) {
        fprintf(stderr, "kernel_launch: ws too small: need %zu have %zu\n", off, ws_size);
        return;
    }

    prep_weights<<<G4_ * H_ / 256, 256, 0, stream>>>(Wih, Whh, bih, bhh, Wc, Wcat, bc);
    prep_w1<<<H_ * H_ / 256, 256, 0, stream>>>(W1, W1b);
    prep_w2<<<16 * H_ / 256, 256, 0, stream>>>(W2, W2b);
    prep_x<<<B_ * H_ / 256, 256, 0, stream>>>(x, hx0, xcat);

    // step 0: K=1024
    lstm_step<1024><<<128, 256, 0, stream>>>(xcat, Wcat, bc, cx0, cbuf, h_hist);

    // zero group counters, then persistent steps 1..325
    hipMemsetAsync(ctr, 0, 4096, stream);
    {
        const unsigned short* Wc_l = Wc;
        const float* bc_l = bc;
        const float* c0_l = cbuf;
        unsigned short* hh_l = h_hist;
        unsigned int* ctr_l = ctr;
        void* args[5] = {(void*)&Wc_l, (void*)&bc_l, (void*)&c0_l, (void*)&hh_l, (void*)&ctr_l};
        hipLaunchCooperativeKernel((const void*)lstm_persist, dim3(256), dim3(256), args, 0, stream);
    }

    mlp_kernel<<<T_ * 4, 256, 0, stream>>>(h_hist, W1b, b1, W2b, b2, out);
}